// Round 7
// baseline (69.569 us; speedup 1.0000x reference)
//
#include <hip/hip_runtime.h>
#include <hip/hip_bf16.h>

typedef __attribute__((ext_vector_type(8))) short short8;
typedef __attribute__((ext_vector_type(4))) float f32x4;
typedef __attribute__((ext_vector_type(4))) int   int4v;

#define IN_F   4096
#define OUT_F  11008
#define KSPLIT 8
#define KPART  (IN_F / KSPLIT)   // 512 k per block
#define BK     64
#define NIT    (KPART / BK)      // 8 chunks
#define DEPTH  3                 // W LDS ring; stage-ahead 2

// f32 -> bf16 round-to-nearest-even
__device__ __forceinline__ short bf16_rne(float f) {
    unsigned u = __builtin_bit_cast(unsigned, f);
    u += 0x7FFFu + ((u >> 16) & 1u);
    return (short)(u >> 16);
}

__device__ __forceinline__ void gld16(const void* g, void* l) {
    __builtin_amdgcn_global_load_lds(
        (const __attribute__((address_space(1))) unsigned int*)g,
        (__attribute__((address_space(3))) unsigned int*)l,
        16, 0, 0);
}

// dequant 8 ints -> short8 bf16 (exact: values in [-3,123])
__device__ __forceinline__ short8 deq8(int4v q0, int4v q1, int zp) {
    short8 r;
#pragma unroll
    for (int j = 0; j < 4; ++j) {
        r[j]     = (short)(__builtin_bit_cast(unsigned, (float)(q0[j] - zp)) >> 16);
        r[j + 4] = (short)(__builtin_bit_cast(unsigned, (float)(q1[j] - zp)) >> 16);
    }
    return r;
}

// ---------- prep: X f32->bf16 cast (blocks 0..127) + bias-init of out (all) --
__global__ __launch_bounds__(256)
void prep(const float* __restrict__ x, const float* __restrict__ bias,
          unsigned short* __restrict__ xb, float* __restrict__ out) {
    const unsigned cid = blockIdx.x * 256 + threadIdx.x;
    if (blockIdx.x < 128) {
        const int i = cid * 8;
        f32x4 a = *(const f32x4*)(x + i);
        f32x4 b = *(const f32x4*)(x + i + 4);
        short8 o;
#pragma unroll
        for (int j = 0; j < 4; ++j) { o[j] = bf16_rne(a[j]); o[j + 4] = bf16_rne(b[j]); }
        *(short8*)(xb + i) = o;
    }
    // binit: 344*256 = 88064 = 64 * (11008/8) exactly
    const unsigned row = cid / (OUT_F / 8);
    const unsigned o   = (cid - row * (OUT_F / 8)) * 8;
    f32x4 b0 = *(const f32x4*)(bias + o);
    f32x4 b1 = *(const f32x4*)(bias + o + 4);
    float* dst = out + (size_t)row * OUT_F + o;
    *(f32x4*)dst = b0;
    *(f32x4*)(dst + 4) = b1;
}

// ---------- main GEMM: 64 cols x 64 tokens; W in LDS ring, X in registers ----
#define STAGE_W(IT) do {                                                      \
    const int _s = (IT) % DEPTH;                                              \
    const int* _wsi = wsrc + (size_t)(IT) * BK;                               \
    gld16(_wsi,             (char*)wt[_s] + tid * 16);                        \
    gld16(_wsi + 16 * IN_F, (char*)wt[_s] + 4096  + tid * 16);                \
    gld16(_wsi + 32 * IN_F, (char*)wt[_s] + 8192  + tid * 16);                \
    gld16(_wsi + 48 * IN_F, (char*)wt[_s] + 12288 + tid * 16);                \
} while (0)

// X chunk IT -> register set S (4 token-groups x 2 k-steps, 16B each).
// "memory" clobber pins queue order vs the gld16 builtins (exact vmcnt math).
#define XLOAD(IT, S) do {                                                     \
    const size_t _o = (size_t)(IT) * 128;                                     \
    asm volatile("global_load_dwordx4 %0, %2, off\n\t"                        \
                 "global_load_dwordx4 %1, %2, off offset:64"                  \
        : "=&v"(xf##S##0a), "=&v"(xf##S##0b) : "v"(xq0 + _o) : "memory");     \
    asm volatile("global_load_dwordx4 %0, %2, off\n\t"                        \
                 "global_load_dwordx4 %1, %2, off offset:64"                  \
        : "=&v"(xf##S##1a), "=&v"(xf##S##1b) : "v"(xq1 + _o) : "memory");     \
    asm volatile("global_load_dwordx4 %0, %2, off\n\t"                        \
                 "global_load_dwordx4 %1, %2, off offset:64"                  \
        : "=&v"(xf##S##2a), "=&v"(xf##S##2b) : "v"(xq2 + _o) : "memory");     \
    asm volatile("global_load_dwordx4 %0, %2, off\n\t"                        \
                 "global_load_dwordx4 %1, %2, off offset:64"                  \
        : "=&v"(xf##S##3a), "=&v"(xf##S##3b) : "v"(xq3 + _o) : "memory");     \
} while (0)

// Chunk compute: dequant own 16-col W slice once, 8 MFMA with X register set S.
#define COMPUTE(SL, S) do {                                                   \
    const char* _wb = (const char*)wt[SL] + wrow_off;                         \
    int4v _q00 = *(const int4v*)(_wb + cw00);                                 \
    int4v _q01 = *(const int4v*)(_wb + cw01);                                 \
    int4v _q10 = *(const int4v*)(_wb + cw10);                                 \
    int4v _q11 = *(const int4v*)(_wb + cw11);                                 \
    short8 _B0 = deq8(_q00, _q01, zp);                                        \
    short8 _B1 = deq8(_q10, _q11, zp);                                        \
    acc0 = __builtin_amdgcn_mfma_f32_16x16x32_bf16(xf##S##0a, _B0, acc0, 0, 0, 0); \
    acc0 = __builtin_amdgcn_mfma_f32_16x16x32_bf16(xf##S##0b, _B1, acc0, 0, 0, 0); \
    acc1 = __builtin_amdgcn_mfma_f32_16x16x32_bf16(xf##S##1a, _B0, acc1, 0, 0, 0); \
    acc1 = __builtin_amdgcn_mfma_f32_16x16x32_bf16(xf##S##1b, _B1, acc1, 0, 0, 0); \
    acc2 = __builtin_amdgcn_mfma_f32_16x16x32_bf16(xf##S##2a, _B0, acc2, 0, 0, 0); \
    acc2 = __builtin_amdgcn_mfma_f32_16x16x32_bf16(xf##S##2b, _B1, acc2, 0, 0, 0); \
    acc3 = __builtin_amdgcn_mfma_f32_16x16x32_bf16(xf##S##3a, _B0, acc3, 0, 0, 0); \
    acc3 = __builtin_amdgcn_mfma_f32_16x16x32_bf16(xf##S##3b, _B1, acc3, 0, 0, 0); \
} while (0)

__global__ __launch_bounds__(256, 3)
void qlin7(const unsigned short* __restrict__ xb, const int* __restrict__ w,
           const float* __restrict__ scale_p, const int* __restrict__ zp_p,
           float* __restrict__ out)
{
    __shared__ __align__(16) int wt[DEPTH][64 * BK];   // 3 x 16KB -> 3 blocks/CU

    const int tid  = threadIdx.x;
    const int lane = tid & 63;
    const int wv   = tid >> 6;      // wave -> 16-col slice
    const int l15  = lane & 15;
    const int lg   = lane >> 4;

    const int ob = blockIdx.x >> 3;          // 172 col-tiles
    const int kh = blockIdx.x & 7;           // K eighth
    const int o0 = ob * 64;
    const int kb = kh * KPART;

    const int   zp    = zp_p[0];
    const float scale = scale_p[0];

    // W staging source (both-sides swizzle: chunk ^ row&7 folded into global addr)
    const int wr = tid >> 4;
    const int wc = (tid & 15) ^ (wr & 7);
    const int* wsrc = w + (size_t)(o0 + wr) * IN_F + kb + wc * 4;

    // X register-load bases: tg t -> row t*16+l15, k = kb + lg*8 (+128B/chunk)
    const char* xq0 = (const char*)(xb + (size_t)(0 * 16 + l15) * IN_F + kb + lg * 8);
    const char* xq1 = (const char*)(xb + (size_t)(1 * 16 + l15) * IN_F + kb + lg * 8);
    const char* xq2 = (const char*)(xb + (size_t)(2 * 16 + l15) * IN_F + kb + lg * 8);
    const char* xq3 = (const char*)(xb + (size_t)(3 * 16 + l15) * IN_F + kb + lg * 8);

    // W LDS read offsets (swizzled, 256B row pitch)
    const int rswz = l15 & 7;
    const int wrow_off = (wv * 16 + l15) * 256;
    const int cw00 = ((lg * 2    ) ^ rswz) * 16;
    const int cw01 = ((lg * 2 + 1) ^ rswz) * 16;
    const int cw10 = ((8 + lg * 2    ) ^ rswz) * 16;
    const int cw11 = ((8 + lg * 2 + 1) ^ rswz) * 16;

    f32x4 acc0 = {0.f, 0.f, 0.f, 0.f};
    f32x4 acc1 = {0.f, 0.f, 0.f, 0.f};
    f32x4 acc2 = {0.f, 0.f, 0.f, 0.f};
    f32x4 acc3 = {0.f, 0.f, 0.f, 0.f};

    // X register double-buffer, named (rule #20), 2 sets x 8 x short8
    short8 xfA0a, xfA0b, xfA1a, xfA1b, xfA2a, xfA2b, xfA3a, xfA3b;
    short8 xfB0a, xfB0b, xfB1a, xfB1b, xfB2a, xfB2b, xfB3a, xfB3b;

    // Prologue queue: [W0(4), X0(8), W1(4)]
    STAGE_W(0);
    XLOAD(0, A);
    STAGE_W(1);

    // Steady state per it: wait vmcnt(4) (retires W(it)+X(it); W(it+1) stays
    // in flight), barrier (cross-wave LDS visibility + slot-reuse seal),
    // issue X(it+1) then W(it+2), compute chunk it. Last it: vmcnt(0).
#pragma unroll
    for (int it = 0; it < NIT; ++it) {
        if (it < NIT - 1) asm volatile("s_waitcnt vmcnt(4)" ::: "memory");
        else              asm volatile("s_waitcnt vmcnt(0)" ::: "memory");
        __builtin_amdgcn_s_barrier();
        __builtin_amdgcn_sched_barrier(0);   // rule #18: pin MFMA after the wait
        if (it + 1 < NIT) {
            if ((it + 1) & 1) XLOAD(it + 1, B);
            else              XLOAD(it + 1, A);
        }
        if (it + 2 < NIT) STAGE_W(it + 2);
        if (it & 1) COMPUTE(it % DEPTH, B);
        else        COMPUTE(it % DEPTH, A);
    }

    // Epilogue: D col = lane&15, row = (lane>>4)*4 + reg. K-split partials
    // atomically accumulate onto bias-initialized out.
    {
        const int o = o0 + wv * 16 + l15;
        float* op = out + o;
#pragma unroll
        for (int r = 0; r < 4; ++r) {
            const int tr = lg * 4 + r;
            unsafeAtomicAdd(op + (size_t)(tr     ) * OUT_F, scale * acc0[r]);
            unsafeAtomicAdd(op + (size_t)(tr + 16) * OUT_F, scale * acc1[r]);
            unsafeAtomicAdd(op + (size_t)(tr + 32) * OUT_F, scale * acc2[r]);
            unsafeAtomicAdd(op + (size_t)(tr + 48) * OUT_F, scale * acc3[r]);
        }
    }
}

extern "C" void kernel_launch(void* const* d_in, const int* in_sizes, int n_in,
                              void* d_out, int out_size, void* d_ws, size_t ws_size,
                              hipStream_t stream) {
    const float* x     = (const float*)d_in[0];
    const int*   w     = (const int*)d_in[1];
    const float* scale = (const float*)d_in[2];
    const int*   zp    = (const int*)d_in[3];
    const float* bias  = (const float*)d_in[4];
    float*       out   = (float*)d_out;
    unsigned short* xbf = (unsigned short*)d_ws;   // 512 KB of d_ws

    prep<<<dim3(344), dim3(256), 0, stream>>>(x, bias, xbf, out);
    qlin7<<<dim3((OUT_F / 64) * KSPLIT), dim3(256), 0, stream>>>(xbf, w, scale, zp, out);
}

// Round 8
// 47.709 us; speedup vs baseline: 1.4582x; 1.4582x over previous
//
#include <hip/hip_runtime.h>
#include <hip/hip_bf16.h>

typedef __attribute__((ext_vector_type(8))) short short8;
typedef __attribute__((ext_vector_type(4))) float f32x4;
typedef __attribute__((ext_vector_type(4))) int   int4v;

#define IN_F   4096
#define OUT_F  11008
#define COLS   128               // out-cols per block
#define KSPLIT 8
#define KPART  (IN_F / KSPLIT)   // 512 k per block
#define BK     64
#define NIT    (KPART / BK)      // 8 chunks
#define DEPTH  2                 // LDS ring slots (stage-ahead 1, vmcnt(5))

// f32 -> bf16 round-to-nearest-even
__device__ __forceinline__ short bf16_rne(float f) {
    unsigned u = __builtin_bit_cast(unsigned, f);
    u += 0x7FFFu + ((u >> 16) & 1u);
    return (short)(u >> 16);
}

__device__ __forceinline__ void gld16(const void* g, void* l) {
    __builtin_amdgcn_global_load_lds(
        (const __attribute__((address_space(1))) unsigned int*)g,
        (__attribute__((address_space(3))) unsigned int*)l,
        16, 0, 0);
}

// dequant 8 ints -> short8 bf16 (exact: values in [-3,123])
__device__ __forceinline__ short8 deq8(int4v q0, int4v q1, int zp) {
    short8 r;
#pragma unroll
    for (int j = 0; j < 4; ++j) {
        r[j]     = (short)(__builtin_bit_cast(unsigned, (float)(q0[j] - zp)) >> 16);
        r[j + 4] = (short)(__builtin_bit_cast(unsigned, (float)(q1[j] - zp)) >> 16);
    }
    return r;
}

// ---------- prep: X f32->bf16 cast (blocks 0..127) + bias-init of out (all) --
__global__ __launch_bounds__(256)
void prep(const float* __restrict__ x, const float* __restrict__ bias,
          unsigned short* __restrict__ xb, float* __restrict__ out) {
    const unsigned cid = blockIdx.x * 256 + threadIdx.x;
    if (blockIdx.x < 128) {
        const int i = cid * 8;
        f32x4 a = *(const f32x4*)(x + i);
        f32x4 b = *(const f32x4*)(x + i + 4);
        short8 o;
#pragma unroll
        for (int j = 0; j < 4; ++j) { o[j] = bf16_rne(a[j]); o[j + 4] = bf16_rne(b[j]); }
        *(short8*)(xb + i) = o;
    }
    const unsigned row = cid / (OUT_F / 8);
    const unsigned o   = (cid - row * (OUT_F / 8)) * 8;
    f32x4 b0 = *(const f32x4*)(bias + o);
    f32x4 b1 = *(const f32x4*)(bias + o + 4);
    float* dst = out + (size_t)row * OUT_F + o;
    *(f32x4*)dst = b0;
    *(f32x4*)(dst + 4) = b1;
}

// ---------- main GEMM: 128 cols x 64 tokens, 8 waves own 16-col slices -------
// Stage chunk IT into ring slot IT&1: W 128x64 int32 (32KB, 4 gld/thr),
// X 64x64 bf16 (8KB, 1 gld/thr). Sources pre-swizzled (chunk ^ row&7),
// LDS dest linear (rule #21). 5 vmem instr per wave per stage.
#define STAGE(IT) do {                                                        \
    const int _s = (IT) & (DEPTH - 1);                                        \
    const int* _wsi = wsrc + (size_t)(IT) * BK;                               \
    gld16(_wsi,             (char*)wt[_s] + tid * 16);                        \
    gld16(_wsi + 32 * IN_F, (char*)wt[_s] + 8192  + tid * 16);                \
    gld16(_wsi + 64 * IN_F, (char*)wt[_s] + 16384 + tid * 16);                \
    gld16(_wsi + 96 * IN_F, (char*)wt[_s] + 24576 + tid * 16);                \
    gld16(xsrc + (size_t)(IT) * BK, (char*)xt[_s] + tid * 16);                \
} while (0)

// One chunk (BK=64): dequant own 16-col W slice once (2 k-step B-frags),
// then 4 token-groups x 2 k-steps = 8 MFMA.  (r6-verbatim)
#define COMPUTE(S) do {                                                       \
    const char* _wb = (const char*)wt[S] + wrow_off;                          \
    int4v _q00 = *(const int4v*)(_wb + cw00);                                 \
    int4v _q01 = *(const int4v*)(_wb + cw01);                                 \
    int4v _q10 = *(const int4v*)(_wb + cw10);                                 \
    int4v _q11 = *(const int4v*)(_wb + cw11);                                 \
    short8 _B0 = deq8(_q00, _q01, zp);                                        \
    short8 _B1 = deq8(_q10, _q11, zp);                                        \
    const char* _xb = (const char*)xt[S] + arow;                              \
    short8 _a;                                                                \
    _a = *(const short8*)(_xb +        ca0);                                  \
    acc0 = __builtin_amdgcn_mfma_f32_16x16x32_bf16(_a, _B0, acc0, 0, 0, 0);   \
    _a = *(const short8*)(_xb +        ca1);                                  \
    acc0 = __builtin_amdgcn_mfma_f32_16x16x32_bf16(_a, _B1, acc0, 0, 0, 0);   \
    _a = *(const short8*)(_xb + 2048 + ca0);                                  \
    acc1 = __builtin_amdgcn_mfma_f32_16x16x32_bf16(_a, _B0, acc1, 0, 0, 0);   \
    _a = *(const short8*)(_xb + 2048 + ca1);                                  \
    acc1 = __builtin_amdgcn_mfma_f32_16x16x32_bf16(_a, _B1, acc1, 0, 0, 0);   \
    _a = *(const short8*)(_xb + 4096 + ca0);                                  \
    acc2 = __builtin_amdgcn_mfma_f32_16x16x32_bf16(_a, _B0, acc2, 0, 0, 0);   \
    _a = *(const short8*)(_xb + 4096 + ca1);                                  \
    acc2 = __builtin_amdgcn_mfma_f32_16x16x32_bf16(_a, _B1, acc2, 0, 0, 0);   \
    _a = *(const short8*)(_xb + 6144 + ca0);                                  \
    acc3 = __builtin_amdgcn_mfma_f32_16x16x32_bf16(_a, _B0, acc3, 0, 0, 0);   \
    _a = *(const short8*)(_xb + 6144 + ca1);                                  \
    acc3 = __builtin_amdgcn_mfma_f32_16x16x32_bf16(_a, _B1, acc3, 0, 0, 0);   \
} while (0)

__global__ __launch_bounds__(512, 4)
void qlin8(const unsigned short* __restrict__ xb, const int* __restrict__ w,
           const float* __restrict__ scale_p, const int* __restrict__ zp_p,
           float* __restrict__ out)
{
    __shared__ __align__(16) int            wt[DEPTH][COLS * BK]; // 2 x 32KB
    __shared__ __align__(16) unsigned short xt[DEPTH][64 * BK];   // 2 x 8KB  (80KB -> 2 blk/CU)

    const int tid  = threadIdx.x;
    const int lane = tid & 63;
    const int wv   = tid >> 6;      // wave 0..7 -> 16-col slice
    const int l15  = lane & 15;
    const int lg   = lane >> 4;

    const int ob = blockIdx.x >> 3;          // 86 col-tiles
    const int kh = blockIdx.x & 7;           // K eighth
    const int o0 = ob * COLS;
    const int kb = kh * KPART;

    const int   zp    = zp_p[0];
    const float scale = scale_p[0];

    // W staging: thread t -> rows (t>>4)+{0,32,64,96}, chunk (t&15)^(row&7).
    // (row+32k)&7 == row&7, so one swizzled base serves all 4 slices.
    const int wr = tid >> 4;                 // 0..31
    const int wc = (tid & 15) ^ (wr & 7);
    const int* wsrc = w + (size_t)(o0 + wr) * IN_F + kb + wc * 4;

    // X staging: thread t -> row t>>3 (0..63), chunk (t&7)^(row&7).
    const int xr = tid >> 3;
    const int xc = (tid & 7) ^ (xr & 7);
    const unsigned short* xsrc = xb + (size_t)xr * IN_F + kb + xc * 8;

    // Read-side swizzle (r6-verbatim): B row = wv*16+l15, A row = g*16+l15.
    const int rswz = l15 & 7;
    const int wrow_off = (wv * 16 + l15) * 256;          // W LDS row (256B pitch)
    const int cw00 = ((lg * 2    ) ^ rswz) * 16;
    const int cw01 = ((lg * 2 + 1) ^ rswz) * 16;
    const int cw10 = ((8 + lg * 2    ) ^ rswz) * 16;
    const int cw11 = ((8 + lg * 2 + 1) ^ rswz) * 16;
    const int arow = l15 * 128;                          // X LDS row (128B pitch)
    const int ca0  = ((lg    ) ^ rswz) * 16;
    const int ca1  = ((4 + lg) ^ rswz) * 16;

    f32x4 acc0 = {0.f, 0.f, 0.f, 0.f};
    f32x4 acc1 = {0.f, 0.f, 0.f, 0.f};
    f32x4 acc2 = {0.f, 0.f, 0.f, 0.f};
    f32x4 acc3 = {0.f, 0.f, 0.f, 0.f};

    // Prologue: 2 chunks in flight (10 vmem instrs/wave)
    STAGE(0);
    STAGE(1);

    // Window it: vmcnt(5) -> chunk it landed, chunk it+1 stays in flight;
    // barrier (cross-wave visibility); compute; barrier (seal slot it&1);
    // stage it+2 into slot it&1.
#pragma unroll
    for (int it = 0; it < NIT; ++it) {
        if (it < NIT - 1) asm volatile("s_waitcnt vmcnt(5)" ::: "memory");
        else              asm volatile("s_waitcnt vmcnt(0)" ::: "memory");
        __builtin_amdgcn_s_barrier();
        COMPUTE(it & 1);
        if (it + 2 < NIT) {
            __builtin_amdgcn_s_barrier();
            STAGE(it + 2);
        }
    }

    // Epilogue: D col = lane&15, row = (lane>>4)*4 + reg. K-split partials
    // atomically accumulate onto bias-initialized out.
    {
        const int o = o0 + wv * 16 + l15;
        float* op = out + o;
#pragma unroll
        for (int r = 0; r < 4; ++r) {
            const int tr = lg * 4 + r;
            unsafeAtomicAdd(op + (size_t)(tr     ) * OUT_F, scale * acc0[r]);
            unsafeAtomicAdd(op + (size_t)(tr + 16) * OUT_F, scale * acc1[r]);
            unsafeAtomicAdd(op + (size_t)(tr + 32) * OUT_F, scale * acc2[r]);
            unsafeAtomicAdd(op + (size_t)(tr + 48) * OUT_F, scale * acc3[r]);
        }
    }
}

extern "C" void kernel_launch(void* const* d_in, const int* in_sizes, int n_in,
                              void* d_out, int out_size, void* d_ws, size_t ws_size,
                              hipStream_t stream) {
    const float* x     = (const float*)d_in[0];
    const int*   w     = (const int*)d_in[1];
    const float* scale = (const float*)d_in[2];
    const int*   zp    = (const int*)d_in[3];
    const float* bias  = (const float*)d_in[4];
    float*       out   = (float*)d_out;
    unsigned short* xbf = (unsigned short*)d_ws;   // 512 KB of d_ws

    prep<<<dim3(344), dim3(256), 0, stream>>>(x, bias, xbf, out);
    qlin8<<<dim3((OUT_F / COLS) * KSPLIT), dim3(512), 0, stream>>>(xbf, w, scale, zp, out);
}